// Round 1
// baseline (596.834 us; speedup 1.0000x reference)
//
#include <hip/hip_runtime.h>

#define HID 64
#define IN_DIM 128

// ---------------- kernels ----------------

__global__ __launch_bounds__(256) void k_init_deg(float* __restrict__ deg, int N) {
    int i = blockIdx.x * blockDim.x + threadIdx.x;
    if (i < N) deg[i] = 1.0f;  // self-loop
}

__global__ __launch_bounds__(256) void k_deg_edges(const int* __restrict__ eidx,
                                                   float* __restrict__ deg, int E) {
    int e = blockIdx.x * blockDim.x + threadIdx.x;
    if (e < E) atomicAdd(&deg[eidx[E + e]], 1.0f);  // dst = eidx[E + e]
}

__global__ __launch_bounds__(256) void k_dinv(float* __restrict__ deg, int N) {
    int i = blockIdx.x * blockDim.x + threadIdx.x;
    if (i < N) deg[i] = rsqrtf(deg[i]);
}

// Per node: h = relu(x@W_in + b_in); hw = h@W_g; hws = hw*dinv; agg = hws*dinv (self-loop)
__global__ __launch_bounds__(256) void k_dense(const float* __restrict__ x,
                                               const float* __restrict__ W_in,
                                               const float* __restrict__ b_in,
                                               const float* __restrict__ W_g,
                                               const float* __restrict__ dinv,
                                               float* __restrict__ hws,
                                               float* __restrict__ agg, int N) {
    __shared__ float xs[4][IN_DIM];
    __shared__ float hs[4][HID];
    const int wid  = threadIdx.x >> 6;
    const int lane = threadIdx.x & 63;
    int node = blockIdx.x * 4 + wid;
    if (node >= N) node = N - 1;  // clamp: duplicate work, same value written

    // stage x row (128 floats) via 2 coalesced loads per lane
    xs[wid][lane]      = x[node * IN_DIM + lane];
    xs[wid][lane + 64] = x[node * IN_DIM + lane + 64];
    __syncthreads();

    float acc = b_in[lane];
#pragma unroll 8
    for (int k = 0; k < IN_DIM; ++k)
        acc = fmaf(xs[wid][k], W_in[k * HID + lane], acc);
    acc = fmaxf(acc, 0.0f);  // ReLU
    hs[wid][lane] = acc;
    __syncthreads();

    float a2 = 0.0f;
#pragma unroll 8
    for (int k = 0; k < HID; ++k)
        a2 = fmaf(hs[wid][k], W_g[k * HID + lane], a2);

    const float di = dinv[node];
    const float s = a2 * di;
    hws[node * HID + lane] = s;
    agg[node * HID + lane] = s * di;  // self-loop contribution seeds agg
}

// one wave per edge: agg[d][j] += hws[s][j] * dinv[d]
__global__ __launch_bounds__(256) void k_scatter(const int* __restrict__ eidx,
                                                 const float* __restrict__ hws,
                                                 const float* __restrict__ dinv,
                                                 float* __restrict__ agg, int E) {
    int t = blockIdx.x * blockDim.x + threadIdx.x;
    int e = t >> 6;
    int j = t & 63;
    if (e >= E) return;
    int s = eidx[e];
    int d = eidx[E + e];
    float v = hws[s * HID + j] * dinv[d];
    atomicAdd(&agg[d * HID + j], v);
}

// out[node] = dot(agg[node] + b_g, W_out) + b_out
__global__ __launch_bounds__(256) void k_final(const float* __restrict__ agg,
                                               const float* __restrict__ b_g,
                                               const float* __restrict__ W_out,
                                               const float* __restrict__ b_out,
                                               float* __restrict__ out, int N) {
    const int wid  = threadIdx.x >> 6;
    const int lane = threadIdx.x & 63;
    int node = blockIdx.x * 4 + wid;
    if (node >= N) node = N - 1;
    float v = (agg[node * HID + lane] + b_g[lane]) * W_out[lane];
#pragma unroll
    for (int off = 32; off > 0; off >>= 1)
        v += __shfl_down(v, off, 64);
    if (lane == 0) out[node] = v + b_out[0];
}

// ---------------- launch ----------------

extern "C" void kernel_launch(void* const* d_in, const int* in_sizes, int n_in,
                              void* d_out, int out_size, void* d_ws, size_t ws_size,
                              hipStream_t stream) {
    const float* x     = (const float*)d_in[0];
    const int*   eidx  = (const int*)d_in[1];
    const float* W_in  = (const float*)d_in[2];
    const float* b_in  = (const float*)d_in[3];
    const float* W_g   = (const float*)d_in[4];
    const float* b_g   = (const float*)d_in[5];
    const float* W_out = (const float*)d_in[6];
    const float* b_out = (const float*)d_in[7];
    float* out = (float*)d_out;

    const int N = in_sizes[0] / IN_DIM;   // 100000
    const int E = in_sizes[1] / 2;        // 1600000

    // workspace layout (floats): dinv[Npad] | hws[N*64] | agg[N*64]
    const int Npad = (N + 63) & ~63;
    float* dinv = (float*)d_ws;
    float* hws  = dinv + Npad;
    float* agg  = hws + (size_t)N * HID;

    k_init_deg<<<(N + 255) / 256, 256, 0, stream>>>(dinv, N);
    k_deg_edges<<<(E + 255) / 256, 256, 0, stream>>>(eidx, dinv, E);
    k_dinv<<<(N + 255) / 256, 256, 0, stream>>>(dinv, N);
    k_dense<<<(N + 3) / 4, 256, 0, stream>>>(x, W_in, b_in, W_g, dinv, hws, agg, N);
    {
        long long threads = (long long)E * 64;
        int blocks = (int)((threads + 255) / 256);
        k_scatter<<<blocks, 256, 0, stream>>>(eidx, hws, dinv, agg, E);
    }
    k_final<<<(N + 3) / 4, 256, 0, stream>>>(agg, b_g, W_out, b_out, out, N);
}

// Round 2
// 325.023 us; speedup vs baseline: 1.8363x; 1.8363x over previous
//
#include <hip/hip_runtime.h>

#define HID 64
#define IN_DIM 128

// ---------------- kernels ----------------

__global__ __launch_bounds__(256) void k_init_deg(float* __restrict__ deg, int N) {
    int i = blockIdx.x * blockDim.x + threadIdx.x;
    if (i < N) deg[i] = 1.0f;  // self-loop
}

__global__ __launch_bounds__(256) void k_deg_edges(const int* __restrict__ eidx,
                                                   float* __restrict__ deg, int E) {
    int e = blockIdx.x * blockDim.x + threadIdx.x;
    if (e < E) atomicAdd(&deg[eidx[E + e]], 1.0f);  // dst = eidx[E + e]
}

__global__ __launch_bounds__(256) void k_dinv(float* __restrict__ deg, int N) {
    int i = blockIdx.x * blockDim.x + threadIdx.x;
    if (i < N) deg[i] = rsqrtf(deg[i]);
}

// Per node (one wave each): h = relu(x@W_in + b_in); hw = h@W_g;
// z = dot(hw, W_out) [scalar]; zs[node] = z*dinv[node]; acc[node] = zs[node] (self-loop seed).
__global__ __launch_bounds__(256) void k_dense(const float* __restrict__ x,
                                               const float* __restrict__ W_in,
                                               const float* __restrict__ b_in,
                                               const float* __restrict__ W_g,
                                               const float* __restrict__ W_out,
                                               const float* __restrict__ dinv,
                                               float* __restrict__ zs,
                                               float* __restrict__ acc, int N) {
    __shared__ float xs[4][IN_DIM];
    __shared__ float hs[4][HID];
    const int wid  = threadIdx.x >> 6;
    const int lane = threadIdx.x & 63;
    int node = blockIdx.x * 4 + wid;
    if (node >= N) node = N - 1;  // clamp: duplicate waves write identical values

    // stage x row (128 floats) via 2 coalesced loads per lane
    xs[wid][lane]      = x[node * IN_DIM + lane];
    xs[wid][lane + 64] = x[node * IN_DIM + lane + 64];
    __syncthreads();

    float a1 = b_in[lane];
#pragma unroll 8
    for (int k = 0; k < IN_DIM; ++k)
        a1 = fmaf(xs[wid][k], W_in[k * HID + lane], a1);
    a1 = fmaxf(a1, 0.0f);  // ReLU
    hs[wid][lane] = a1;
    __syncthreads();

    float a2 = 0.0f;
#pragma unroll 8
    for (int k = 0; k < HID; ++k)
        a2 = fmaf(hs[wid][k], W_g[k * HID + lane], a2);

    // z = dot(hw, W_out) via butterfly reduce (all lanes end with z)
    float v = a2 * W_out[lane];
#pragma unroll
    for (int off = 32; off > 0; off >>= 1)
        v += __shfl_xor(v, off, 64);

    if (lane == 0) {
        const float di = dinv[node];
        const float s = v * di;   // zs = z * dinv[src]
        zs[node]  = s;
        acc[node] = s;            // self-loop: dinv[d]*z[d] seeds the sum
    }
}

// one thread per edge: acc[dst] += zs[src]   (scalar atomics, L2-resident)
__global__ __launch_bounds__(256) void k_scatter(const int* __restrict__ eidx,
                                                 const float* __restrict__ zs,
                                                 float* __restrict__ acc, int E) {
    int e = blockIdx.x * blockDim.x + threadIdx.x;
    if (e >= E) return;
    int s = eidx[e];
    int d = eidx[E + e];
    atomicAdd(&acc[d], zs[s]);
}

// out[i] = dinv[i]*acc[i] + (b_g . W_out + b_out)
__global__ __launch_bounds__(256) void k_final(const float* __restrict__ dinv,
                                               const float* __restrict__ acc,
                                               const float* __restrict__ b_g,
                                               const float* __restrict__ W_out,
                                               const float* __restrict__ b_out,
                                               float* __restrict__ out, int N) {
    const int lane = threadIdx.x & 63;
    // every wave computes C = b_g . W_out + b_out (butterfly → all lanes)
    float c = b_g[lane] * W_out[lane];
#pragma unroll
    for (int off = 32; off > 0; off >>= 1)
        c += __shfl_xor(c, off, 64);
    c += b_out[0];

    int i = blockIdx.x * blockDim.x + threadIdx.x;
    if (i < N) out[i] = fmaf(dinv[i], acc[i], c);
}

// ---------------- launch ----------------

extern "C" void kernel_launch(void* const* d_in, const int* in_sizes, int n_in,
                              void* d_out, int out_size, void* d_ws, size_t ws_size,
                              hipStream_t stream) {
    const float* x     = (const float*)d_in[0];
    const int*   eidx  = (const int*)d_in[1];
    const float* W_in  = (const float*)d_in[2];
    const float* b_in  = (const float*)d_in[3];
    const float* W_g   = (const float*)d_in[4];
    const float* b_g   = (const float*)d_in[5];
    const float* W_out = (const float*)d_in[6];
    const float* b_out = (const float*)d_in[7];
    float* out = (float*)d_out;

    const int N = in_sizes[0] / IN_DIM;   // 100000
    const int E = in_sizes[1] / 2;        // 1600000

    // workspace layout (floats): dinv[Npad] | zs[Npad] | acc[Npad]   (~1.2 MB)
    const int Npad = (N + 63) & ~63;
    float* dinv = (float*)d_ws;
    float* zs   = dinv + Npad;
    float* acc  = zs + Npad;

    k_init_deg<<<(N + 255) / 256, 256, 0, stream>>>(dinv, N);
    k_deg_edges<<<(E + 255) / 256, 256, 0, stream>>>(eidx, dinv, E);
    k_dinv<<<(N + 255) / 256, 256, 0, stream>>>(dinv, N);
    k_dense<<<(N + 3) / 4, 256, 0, stream>>>(x, W_in, b_in, W_g, W_out, dinv, zs, acc, N);
    k_scatter<<<(E + 255) / 256, 256, 0, stream>>>(eidx, zs, acc, E);
    k_final<<<(N + 255) / 256, 256, 0, stream>>>(dinv, acc, b_g, W_out, b_out, out, N);
}

// Round 6
// 208.196 us; speedup vs baseline: 2.8667x; 1.5611x over previous
//
#include <hip/hip_runtime.h>

#define HID 64
#define IN_DIM 128

// ---------------- kernels ----------------

// degree count: one thread per 4 edges (int4 load of dst half)
__global__ __launch_bounds__(256) void k_deg(const int* __restrict__ dst,
                                             int* __restrict__ deg, int E) {
    int t = blockIdx.x * blockDim.x + threadIdx.x;
    int e = t * 4;
    if (e + 3 < E) {
        int4 d4 = *(const int4*)(dst + e);
        atomicAdd(&deg[d4.x], 1);
        atomicAdd(&deg[d4.y], 1);
        atomicAdd(&deg[d4.z], 1);
        atomicAdd(&deg[d4.w], 1);
    } else {
        for (; e < E; ++e) atomicAdd(&deg[dst[e]], 1);
    }
}

// w_eff[j] = sum_j' W_g[j][j'] * W_out[j']   (one wave, tiny)
__global__ __launch_bounds__(64) void k_weff(const float* __restrict__ W_g,
                                             const float* __restrict__ W_out,
                                             float* __restrict__ w_eff) {
    int j = threadIdx.x;
    float s = 0.0f;
#pragma unroll
    for (int jp = 0; jp < HID; ++jp)
        s = fmaf(W_g[j * HID + jp], W_out[jp], s);
    w_eff[j] = s;
}

// Per lane: 2 nodes. h = relu(x@W_in+b_in); z = h . w_eff;
// zs[node] = z*dinv; acc[node] = z*dinv (self-loop seed — k_final applies the
// second dinv factor to the WHOLE accumulator). dinv = rsqrt(deg+1).
__global__ __launch_bounds__(256) void k_dense(const float* __restrict__ x,
                                               const float* __restrict__ W_in,
                                               const float* __restrict__ b_in,
                                               const float* __restrict__ w_eff,
                                               const int* __restrict__ deg,
                                               float* __restrict__ zs,
                                               float* __restrict__ acc, int N) {
    __shared__ float Wl[IN_DIM * HID];   // 32 KB
    __shared__ float weff_l[HID];
    __shared__ float bl[HID];

    for (int i = threadIdx.x; i < IN_DIM * HID; i += 256)
        Wl[i] = W_in[i];
    if (threadIdx.x < HID) {
        weff_l[threadIdx.x] = w_eff[threadIdx.x];
        bl[threadIdx.x]     = b_in[threadIdx.x];
    }
    __syncthreads();

    const int wid  = threadIdx.x >> 6;
    const int lane = threadIdx.x & 63;
    int nA = blockIdx.x * 512 + wid * 128 + lane;
    int nB = nA + 64;
    if (nA >= N) nA = N - 1;   // clamped lanes duplicate-write identical values
    if (nB >= N) nB = N - 1;

    float aA[HID], aB[HID];
#pragma unroll
    for (int j = 0; j < HID; ++j) {
        aA[j] = bl[j];
        aB[j] = bl[j];
    }

    const float4* xA = (const float4*)(x + (size_t)nA * IN_DIM);
    const float4* xB = (const float4*)(x + (size_t)nB * IN_DIM);

    for (int k4 = 0; k4 < IN_DIM / 4; ++k4) {
        float4 xa = xA[k4];
        float4 xb = xB[k4];
        const float fa[4] = {xa.x, xa.y, xa.z, xa.w};
        const float fb[4] = {xb.x, xb.y, xb.z, xb.w};
        const float* wr = Wl + (k4 * 4) * HID;
#pragma unroll
        for (int kk = 0; kk < 4; ++kk) {
            const float4* wv4 = (const float4*)(wr + kk * HID);
            float va = fa[kk], vb = fb[kk];
#pragma unroll
            for (int j4 = 0; j4 < HID / 4; ++j4) {
                float4 wv = wv4[j4];
                aA[4*j4+0] = fmaf(va, wv.x, aA[4*j4+0]);
                aA[4*j4+1] = fmaf(va, wv.y, aA[4*j4+1]);
                aA[4*j4+2] = fmaf(va, wv.z, aA[4*j4+2]);
                aA[4*j4+3] = fmaf(va, wv.w, aA[4*j4+3]);
                aB[4*j4+0] = fmaf(vb, wv.x, aB[4*j4+0]);
                aB[4*j4+1] = fmaf(vb, wv.y, aB[4*j4+1]);
                aB[4*j4+2] = fmaf(vb, wv.z, aB[4*j4+2]);
                aB[4*j4+3] = fmaf(vb, wv.w, aB[4*j4+3]);
            }
        }
    }

    float zA = 0.0f, zB = 0.0f;
#pragma unroll
    for (int j = 0; j < HID; ++j) {
        zA = fmaf(fmaxf(aA[j], 0.0f), weff_l[j], zA);
        zB = fmaf(fmaxf(aB[j], 0.0f), weff_l[j], zB);
    }

    const float dA = rsqrtf((float)deg[nA] + 1.0f);
    const float dB = rsqrtf((float)deg[nB] + 1.0f);
    const float sA = zA * dA;
    const float sB = zB * dB;
    zs[nA]  = sA;
    acc[nA] = sA;   // seed with z*dinv (one factor); k_final applies dinv[d]
    zs[nB]  = sB;
    acc[nB] = sB;
}

// one thread per 2 edges: acc[dst] += zs[src]
__global__ __launch_bounds__(256) void k_scatter(const int* __restrict__ eidx,
                                                 const float* __restrict__ zs,
                                                 float* __restrict__ acc, int E) {
    int t = blockIdx.x * blockDim.x + threadIdx.x;
    int e = t * 2;
    if (e + 1 < E) {
        int2 s2 = *(const int2*)(eidx + e);
        int2 d2 = *(const int2*)(eidx + E + e);
        atomicAdd(&acc[d2.x], zs[s2.x]);
        atomicAdd(&acc[d2.y], zs[s2.y]);
    } else if (e < E) {
        atomicAdd(&acc[eidx[E + e]], zs[eidx[e]]);
    }
}

// out[i] = rsqrt(deg[i]+1)*acc[i] + (b_g . W_out + b_out)
__global__ __launch_bounds__(256) void k_final(const int* __restrict__ deg,
                                               const float* __restrict__ acc,
                                               const float* __restrict__ b_g,
                                               const float* __restrict__ W_out,
                                               const float* __restrict__ b_out,
                                               float* __restrict__ out, int N) {
    const int lane = threadIdx.x & 63;
    float c = b_g[lane] * W_out[lane];
#pragma unroll
    for (int off = 32; off > 0; off >>= 1)
        c += __shfl_xor(c, off, 64);
    c += b_out[0];

    int i = blockIdx.x * blockDim.x + threadIdx.x;
    if (i < N) out[i] = fmaf(rsqrtf((float)deg[i] + 1.0f), acc[i], c);
}

// ---------------- launch ----------------

extern "C" void kernel_launch(void* const* d_in, const int* in_sizes, int n_in,
                              void* d_out, int out_size, void* d_ws, size_t ws_size,
                              hipStream_t stream) {
    const float* x     = (const float*)d_in[0];
    const int*   eidx  = (const int*)d_in[1];
    const float* W_in  = (const float*)d_in[2];
    const float* b_in  = (const float*)d_in[3];
    const float* W_g   = (const float*)d_in[4];
    const float* b_g   = (const float*)d_in[5];
    const float* W_out = (const float*)d_in[6];
    const float* b_out = (const float*)d_in[7];
    float* out = (float*)d_out;

    const int N = in_sizes[0] / IN_DIM;   // 100000
    const int E = in_sizes[1] / 2;        // 1600000

    // workspace (floats/ints): deg[Npad] | zs[Npad] | acc[Npad] | w_eff[64]
    const int Npad = (N + 63) & ~63;
    int*   deg  = (int*)d_ws;
    float* zs   = (float*)d_ws + Npad;
    float* acc  = (float*)d_ws + 2 * (size_t)Npad;
    float* weff = (float*)d_ws + 3 * (size_t)Npad;

    hipMemsetAsync(deg, 0, (size_t)Npad * sizeof(int), stream);
    k_deg<<<(E / 4 + 255) / 256, 256, 0, stream>>>(eidx + E, deg, E);
    k_weff<<<1, 64, 0, stream>>>(W_g, W_out, weff);
    k_dense<<<(N + 511) / 512, 256, 0, stream>>>(x, W_in, b_in, weff, deg, zs, acc, N);
    k_scatter<<<(E / 2 + 255) / 256, 256, 0, stream>>>(eidx, zs, acc, E);
    k_final<<<(N + 255) / 256, 256, 0, stream>>>(deg, acc, b_g, W_out, b_out, out, N);
}

// Round 7
// 192.618 us; speedup vs baseline: 3.0985x; 1.0809x over previous
//
#include <hip/hip_runtime.h>

#define HID 64
#define IN_DIM 128
#define R_DEG 4
#define R_ACC 8
#define DEG_BLOCKS 256

// ---------------- fused: dense-z (blocks [0,nDense)) + deg histogram (rest) ----------------
__global__ __launch_bounds__(256) void k_fused(const float* __restrict__ x,
                                               const float* __restrict__ W_in,
                                               const float* __restrict__ b_in,
                                               const float* __restrict__ W_g,
                                               const float* __restrict__ W_out,
                                               const int* __restrict__ eidx,
                                               int* __restrict__ degR,
                                               float* __restrict__ z,
                                               int N, int E, int Npad, int nDense) {
    __shared__ float Wl[IN_DIM * HID];   // 32 KB
    __shared__ float weff_l[HID];
    __shared__ float bl[HID];

    if ((int)blockIdx.x >= nDense) {
        // ---- degree part: grid-stride over int4 chunks of the dst half ----
        const int bid = blockIdx.x - nDense;
        int* deg = degR + (size_t)(bid & (R_DEG - 1)) * Npad;
        const int4* dst4 = (const int4*)(eidx + E);
        const int nChunk = E >> 2;
        for (int c = bid * 256 + threadIdx.x; c < nChunk; c += DEG_BLOCKS * 256) {
            int4 d4 = dst4[c];
            atomicAdd(&deg[d4.x], 1);
            atomicAdd(&deg[d4.y], 1);
            atomicAdd(&deg[d4.z], 1);
            atomicAdd(&deg[d4.w], 1);
        }
        if (bid == 0 && threadIdx.x == 0) {
            for (int e = nChunk << 2; e < E; ++e) atomicAdd(&degR[eidx[E + e]], 1);
        }
        return;
    }

    // ---- dense part: z[node] = relu(x@W_in + b_in) . (W_g @ W_out) ----
    for (int i = threadIdx.x; i < IN_DIM * HID; i += 256)
        Wl[i] = W_in[i];
    if (threadIdx.x < HID) {
        bl[threadIdx.x] = b_in[threadIdx.x];
        float s = 0.0f;
#pragma unroll
        for (int jp = 0; jp < HID; ++jp)
            s = fmaf(W_g[threadIdx.x * HID + jp], W_out[jp], s);
        weff_l[threadIdx.x] = s;   // w_eff = W_g @ W_out, computed per block
    }
    __syncthreads();

    const int wid  = threadIdx.x >> 6;
    const int lane = threadIdx.x & 63;
    int nA = blockIdx.x * 512 + wid * 128 + lane;
    int nB = nA + 64;
    if (nA >= N) nA = N - 1;   // clamped lanes duplicate-write identical values
    if (nB >= N) nB = N - 1;

    float aA[HID], aB[HID];
#pragma unroll
    for (int j = 0; j < HID; ++j) {
        aA[j] = bl[j];
        aB[j] = bl[j];
    }

    const float4* xA = (const float4*)(x + (size_t)nA * IN_DIM);
    const float4* xB = (const float4*)(x + (size_t)nB * IN_DIM);

    for (int k4 = 0; k4 < IN_DIM / 4; ++k4) {
        float4 xa = xA[k4];
        float4 xb = xB[k4];
        const float fa[4] = {xa.x, xa.y, xa.z, xa.w};
        const float fb[4] = {xb.x, xb.y, xb.z, xb.w};
        const float* wr = Wl + (k4 * 4) * HID;
#pragma unroll
        for (int kk = 0; kk < 4; ++kk) {
            const float4* wv4 = (const float4*)(wr + kk * HID);
            float va = fa[kk], vb = fb[kk];
#pragma unroll
            for (int j4 = 0; j4 < HID / 4; ++j4) {
                float4 wv = wv4[j4];
                aA[4*j4+0] = fmaf(va, wv.x, aA[4*j4+0]);
                aA[4*j4+1] = fmaf(va, wv.y, aA[4*j4+1]);
                aA[4*j4+2] = fmaf(va, wv.z, aA[4*j4+2]);
                aA[4*j4+3] = fmaf(va, wv.w, aA[4*j4+3]);
                aB[4*j4+0] = fmaf(vb, wv.x, aB[4*j4+0]);
                aB[4*j4+1] = fmaf(vb, wv.y, aB[4*j4+1]);
                aB[4*j4+2] = fmaf(vb, wv.z, aB[4*j4+2]);
                aB[4*j4+3] = fmaf(vb, wv.w, aB[4*j4+3]);
            }
        }
    }

    float zA = 0.0f, zB = 0.0f;
#pragma unroll
    for (int j = 0; j < HID; ++j) {
        zA = fmaf(fmaxf(aA[j], 0.0f), weff_l[j], zA);
        zB = fmaf(fmaxf(aB[j], 0.0f), weff_l[j], zB);
    }
    z[nA] = zA;
    z[nB] = zB;
}

// ---------------- dinv + seed: dinv=rsqrt(deg+1); zs=z*dinv; accR[0]=zs; accR[1..7]=0 ----
__global__ __launch_bounds__(256) void k_dinv(const int* __restrict__ degR,
                                              const float* __restrict__ z,
                                              float* __restrict__ dinv,
                                              float* __restrict__ zs,
                                              float* __restrict__ accR,
                                              int N, int Npad) {
    int i = blockIdx.x * blockDim.x + threadIdx.x;
    if (i >= N) return;
    int d = 0;
#pragma unroll
    for (int r = 0; r < R_DEG; ++r) d += degR[(size_t)r * Npad + i];
    float di = rsqrtf((float)d + 1.0f);
    dinv[i] = di;
    float s = z[i] * di;
    zs[i]   = s;
    accR[i] = s;   // self-loop seed in replica 0
#pragma unroll
    for (int r = 1; r < R_ACC; ++r) accR[(size_t)r * Npad + i] = 0.0f;
}

// ---------------- scatter: accR[blk&7][dst] += zs[src] ----------------
__global__ __launch_bounds__(256) void k_scatter(const int* __restrict__ eidx,
                                                 const float* __restrict__ zs,
                                                 float* __restrict__ accR,
                                                 int E, int Npad) {
    float* acc = accR + (size_t)(blockIdx.x & (R_ACC - 1)) * Npad;
    int t = blockIdx.x * blockDim.x + threadIdx.x;
    int e = t * 2;
    if (e + 1 < E) {
        int2 s2 = *(const int2*)(eidx + e);
        int2 d2 = *(const int2*)(eidx + E + e);
        atomicAdd(&acc[d2.x], zs[s2.x]);
        atomicAdd(&acc[d2.y], zs[s2.y]);
    } else if (e < E) {
        atomicAdd(&acc[eidx[E + e]], zs[eidx[e]]);
    }
}

// ---------------- final: out = dinv * (sum of replicas) + (b_g.W_out + b_out) ----------------
__global__ __launch_bounds__(256) void k_final(const float* __restrict__ dinv,
                                               const float* __restrict__ accR,
                                               const float* __restrict__ b_g,
                                               const float* __restrict__ W_out,
                                               const float* __restrict__ b_out,
                                               float* __restrict__ out, int N, int Npad) {
    const int lane = threadIdx.x & 63;
    float c = b_g[lane] * W_out[lane];
#pragma unroll
    for (int off = 32; off > 0; off >>= 1)
        c += __shfl_xor(c, off, 64);
    c += b_out[0];

    int i = blockIdx.x * blockDim.x + threadIdx.x;
    if (i >= N) return;
    float a = 0.0f;
#pragma unroll
    for (int r = 0; r < R_ACC; ++r) a += accR[(size_t)r * Npad + i];
    out[i] = fmaf(dinv[i], a, c);
}

// ---------------- launch ----------------

extern "C" void kernel_launch(void* const* d_in, const int* in_sizes, int n_in,
                              void* d_out, int out_size, void* d_ws, size_t ws_size,
                              hipStream_t stream) {
    const float* x     = (const float*)d_in[0];
    const int*   eidx  = (const int*)d_in[1];
    const float* W_in  = (const float*)d_in[2];
    const float* b_in  = (const float*)d_in[3];
    const float* W_g   = (const float*)d_in[4];
    const float* b_g   = (const float*)d_in[5];
    const float* W_out = (const float*)d_in[6];
    const float* b_out = (const float*)d_in[7];
    float* out = (float*)d_out;

    const int N = in_sizes[0] / IN_DIM;   // 100000
    const int E = in_sizes[1] / 2;        // 1600000

    // ws (floats): degR[4*Npad] | z[Npad] | dinv[Npad] | zs[Npad] | accR[8*Npad]
    const int Npad = (N + 63) & ~63;
    int*   degR = (int*)d_ws;
    float* z    = (float*)d_ws + (size_t)R_DEG * Npad;
    float* dinv = z + Npad;
    float* zs   = dinv + Npad;
    float* accR = zs + Npad;

    hipMemsetAsync(degR, 0, (size_t)R_DEG * Npad * sizeof(int), stream);
    const int nDense = (N + 511) / 512;
    k_fused<<<nDense + DEG_BLOCKS, 256, 0, stream>>>(x, W_in, b_in, W_g, W_out,
                                                     eidx, degR, z, N, E, Npad, nDense);
    k_dinv<<<(N + 255) / 256, 256, 0, stream>>>(degR, z, dinv, zs, accR, N, Npad);
    k_scatter<<<(E / 2 + 255) / 256, 256, 0, stream>>>(eidx, zs, accR, E, Npad);
    k_final<<<(N + 255) / 256, 256, 0, stream>>>(dinv, accR, b_g, W_out, b_out, out, N, Npad);
}

// Round 8
// 189.365 us; speedup vs baseline: 3.1518x; 1.0172x over previous
//
#include <hip/hip_runtime.h>

#define HID 64
#define IN_DIM 128
#define R_DEG 4
#define R_ACC 8
#define DEG_BLOCKS 256

// ---------------- fused: dense-z (blocks [0,nDense)) + deg histogram (rest) ----------------
// Dense: thread-per-node, acc[64] in VGPRs, W via wave-uniform loads (s_load/K$),
// x per-lane float4. No LDS W tile.
__global__ __launch_bounds__(256) void k_fused(const float* __restrict__ x,
                                               const float* __restrict__ W_in,
                                               const float* __restrict__ b_in,
                                               const float* __restrict__ W_g,
                                               const float* __restrict__ W_out,
                                               const int* __restrict__ eidx,
                                               int* __restrict__ degR,
                                               float* __restrict__ z,
                                               int N, int E, int Npad, int nDense) {
    if ((int)blockIdx.x >= nDense) {
        // ---- degree histogram: grid-stride over int4 chunks of the dst half ----
        const int bid = blockIdx.x - nDense;
        int* deg = degR + (size_t)(bid & (R_DEG - 1)) * Npad;
        const int4* dst4 = (const int4*)(eidx + E);
        const int nChunk = E >> 2;
        for (int c = bid * 256 + threadIdx.x; c < nChunk; c += DEG_BLOCKS * 256) {
            int4 d4 = dst4[c];
            atomicAdd(&deg[d4.x], 1);
            atomicAdd(&deg[d4.y], 1);
            atomicAdd(&deg[d4.z], 1);
            atomicAdd(&deg[d4.w], 1);
        }
        if (bid == 0 && threadIdx.x == 0) {
            for (int e = nChunk << 2; e < E; ++e) atomicAdd(&degR[eidx[E + e]], 1);
        }
        return;
    }

    // ---- dense part ----
    __shared__ float weff_l[HID];
    if (threadIdx.x < HID) {
        float s = 0.0f;
#pragma unroll
        for (int jp = 0; jp < HID; ++jp)
            s = fmaf(W_g[threadIdx.x * HID + jp], W_out[jp], s);
        weff_l[threadIdx.x] = s;   // w_eff = W_g @ W_out
    }
    __syncthreads();

    int node = blockIdx.x * 256 + threadIdx.x;
    if (node >= N) node = N - 1;   // clamped threads duplicate-write identical values

    float acc[HID];
#pragma unroll
    for (int j = 0; j < HID; ++j) acc[j] = b_in[j];   // uniform -> s_load

    const float4* xrow = (const float4*)(x + (size_t)node * IN_DIM);
    for (int k4 = 0; k4 < IN_DIM / 4; ++k4) {
        float4 xv = xrow[k4];                          // per-lane global, L1-reused
        const float* wr = W_in + k4 * 4 * HID;         // wave-uniform base
        const float xk[4] = {xv.x, xv.y, xv.z, xv.w};
#pragma unroll
        for (int kk = 0; kk < 4; ++kk) {
#pragma unroll
            for (int j = 0; j < HID; ++j)
                acc[j] = fmaf(xk[kk], wr[kk * HID + j], acc[j]);  // uniform W -> s_load
        }
    }

    float zv = 0.0f;
#pragma unroll
    for (int j = 0; j < HID; ++j)
        zv = fmaf(fmaxf(acc[j], 0.0f), weff_l[j], zv);
    z[node] = zv;
}

// ---------------- dinv + seed: dinv=rsqrt(deg+1); zs=z*dinv; accR[0]=zs; accR[1..7]=0 ----
__global__ __launch_bounds__(256) void k_dinv(const int* __restrict__ degR,
                                              const float* __restrict__ z,
                                              float* __restrict__ dinv,
                                              float* __restrict__ zs,
                                              float* __restrict__ accR,
                                              int N, int Npad) {
    int i = blockIdx.x * blockDim.x + threadIdx.x;
    if (i >= N) return;
    int d = 0;
#pragma unroll
    for (int r = 0; r < R_DEG; ++r) d += degR[(size_t)r * Npad + i];
    float di = rsqrtf((float)d + 1.0f);
    dinv[i] = di;
    float s = z[i] * di;
    zs[i]   = s;
    accR[i] = s;   // self-loop seed in replica 0
#pragma unroll
    for (int r = 1; r < R_ACC; ++r) accR[(size_t)r * Npad + i] = 0.0f;
}

// ---------------- scatter: 4 edges/thread, accR[blk&7][dst] += zs[src] ----------------
__global__ __launch_bounds__(256) void k_scatter(const int* __restrict__ eidx,
                                                 const float* __restrict__ zs,
                                                 float* __restrict__ accR,
                                                 int E, int Npad) {
    float* acc = accR + (size_t)(blockIdx.x & (R_ACC - 1)) * Npad;
    int t = blockIdx.x * blockDim.x + threadIdx.x;
    int e = t * 4;
    if (e + 3 < E) {
        int4 s4 = *(const int4*)(eidx + e);
        int4 d4 = *(const int4*)(eidx + E + e);
        float v0 = zs[s4.x], v1 = zs[s4.y], v2 = zs[s4.z], v3 = zs[s4.w];
        atomicAdd(&acc[d4.x], v0);
        atomicAdd(&acc[d4.y], v1);
        atomicAdd(&acc[d4.z], v2);
        atomicAdd(&acc[d4.w], v3);
    } else {
        for (; e < E; ++e) atomicAdd(&acc[eidx[E + e]], zs[eidx[e]]);
    }
}

// ---------------- final: out = dinv * (sum of replicas) + (b_g.W_out + b_out) ----------------
__global__ __launch_bounds__(256) void k_final(const float* __restrict__ dinv,
                                               const float* __restrict__ accR,
                                               const float* __restrict__ b_g,
                                               const float* __restrict__ W_out,
                                               const float* __restrict__ b_out,
                                               float* __restrict__ out, int N, int Npad) {
    const int lane = threadIdx.x & 63;
    float c = b_g[lane] * W_out[lane];
#pragma unroll
    for (int off = 32; off > 0; off >>= 1)
        c += __shfl_xor(c, off, 64);
    c += b_out[0];

    int i = blockIdx.x * blockDim.x + threadIdx.x;
    if (i >= N) return;
    float a = 0.0f;
#pragma unroll
    for (int r = 0; r < R_ACC; ++r) a += accR[(size_t)r * Npad + i];
    out[i] = fmaf(dinv[i], a, c);
}

// ---------------- launch ----------------

extern "C" void kernel_launch(void* const* d_in, const int* in_sizes, int n_in,
                              void* d_out, int out_size, void* d_ws, size_t ws_size,
                              hipStream_t stream) {
    const float* x     = (const float*)d_in[0];
    const int*   eidx  = (const int*)d_in[1];
    const float* W_in  = (const float*)d_in[2];
    const float* b_in  = (const float*)d_in[3];
    const float* W_g   = (const float*)d_in[4];
    const float* b_g   = (const float*)d_in[5];
    const float* W_out = (const float*)d_in[6];
    const float* b_out = (const float*)d_in[7];
    float* out = (float*)d_out;

    const int N = in_sizes[0] / IN_DIM;   // 100000
    const int E = in_sizes[1] / 2;        // 1600000

    // ws (floats): degR[4*Npad] | z[Npad] | dinv[Npad] | zs[Npad] | accR[8*Npad]
    const int Npad = (N + 63) & ~63;
    int*   degR = (int*)d_ws;
    float* z    = (float*)d_ws + (size_t)R_DEG * Npad;
    float* dinv = z + Npad;
    float* zs   = dinv + Npad;
    float* accR = zs + Npad;

    hipMemsetAsync(degR, 0, (size_t)R_DEG * Npad * sizeof(int), stream);
    const int nDense = (N + 255) / 256;
    k_fused<<<nDense + DEG_BLOCKS, 256, 0, stream>>>(x, W_in, b_in, W_g, W_out,
                                                     eidx, degR, z, N, E, Npad, nDense);
    k_dinv<<<(N + 255) / 256, 256, 0, stream>>>(degR, z, dinv, zs, accR, N, Npad);
    k_scatter<<<(E / 4 + 255) / 256, 256, 0, stream>>>(eidx, zs, accR, E, Npad);
    k_final<<<(N + 255) / 256, 256, 0, stream>>>(dinv, accR, b_g, W_out, b_out, out, N, Npad);
}